// Round 19
// baseline (508.216 us; speedup 1.0000x reference)
//
#include <hip/hip_runtime.h>
#include <math.h>

// B=32, R=16384, C=16, IC=16, OC=16, 3 routing iterations.
// x: (B,C,IC) fp32; W: (R,C,OC,IC) fp32 (256 MB); out: (B,C,OC) fp32.
//
// R19 accounting model (fits R10..R18): measured dur includes a ~160 us
// harness workspace-poison fill (1.07 GB @ 6.7 TB/s) -- fixed tax. Our GPU
// time in R18 was ~310 us: conv 60 + 3 x route 80 + small 10.
// Lever: iter-1 needs only wsum = sum_r W (E1 = wsum . x), so FUSE the r-sum
// into the conversion kernel and DELETE the MODE-0 route pass entirely:
//   k_convsum: dense fp32 read (256 MB) + W16 fragment write (128 MB)
//              + per-block fp32 partials (16 MB, atomic-free)
//   k_wred_v1: 1024-way partial reduce + v1 = squash(wsum.x/R)  (R4-proven)
//   2 x k_route (MODE 1) on W16 (L3-resident, written by conv)
// Carried: W16 fragment layout + route math (R15-R18, absmax 3.9e-3 vs
// threshold 1.5e-2), full per-wave prefetch, LDS-tree epilogue.
// Lessons kept: no cooperative launch (R12); no fusion barriers (R16).

typedef _Float16 half8_t __attribute__((ext_vector_type(8)));
typedef float f32x16_t __attribute__((ext_vector_type(16)));

// ---------------------------------------------------------------------------
// k_convsum: grid 1024 x 256. Block b: r-window [b*16,+16). Thread: (c,o) =
// (tid>>4, tid&15). Per r: read W[r][c][o][0..15] (64 B dense; wave = 4 KB
// contiguous), accumulate ws[i] += w[i], convert to fp16, write the two
// 16 B fragment chunks of W16. After loop: store ws to part[b] (contiguous).
// W16 layout (halves): ((c*8192 + (r>>1))*64 + ((r&1)*16 + o + 32*kh))*8,
// element j = W[r][c][o][8kh+j] -- the mfma_32x32x16 A-fragment (R17-proven).
// ---------------------------------------------------------------------------
__global__ __launch_bounds__(256) void k_convsum(const float4* __restrict__ W4,
                                                 _Float16* __restrict__ W16,
                                                 float* __restrict__ part) {
    const int b = blockIdx.x;                      // [0,1024)
    const int tid = threadIdx.x;
    const int c = tid >> 4, o = tid & 15;
    float ws[16];
    #pragma unroll
    for (int i = 0; i < 16; ++i) ws[i] = 0.f;

    #pragma unroll 2
    for (int rr = 0; rr < 16; ++rr) {
        const int r = b * 16 + rr;
        const float4* src = W4 + ((size_t)(r * 16 + c) * 16 + o) * 4;
        float4 a0 = src[0], a1 = src[1], a2 = src[2], a3 = src[3];
        float w[16] = {a0.x, a0.y, a0.z, a0.w, a1.x, a1.y, a1.z, a1.w,
                       a2.x, a2.y, a2.z, a2.w, a3.x, a3.y, a3.z, a3.w};
        #pragma unroll
        for (int i = 0; i < 16; ++i) ws[i] += w[i];
        half8_t h0, h1;
        #pragma unroll
        for (int j = 0; j < 8; ++j) {
            h0[j] = (_Float16)w[j];
            h1[j] = (_Float16)w[8 + j];
        }
        size_t fb = (size_t)(c * 8192 + (r >> 1)) * 64 + (r & 1) * 16 + o;
        *(uint4*)(W16 + fb * 8)            = *(uint4*)&h0;   // kh=0
        *(uint4*)(W16 + (fb + 32) * 8)     = *(uint4*)&h1;   // kh=1
    }
    float* dst = part + (size_t)b * 4096 + (c * 16 + o) * 16;
    #pragma unroll
    for (int q = 0; q < 4; ++q)
        *(float4*)(dst + q * 4) = make_float4(ws[q*4], ws[q*4+1], ws[q*4+2], ws[q*4+3]);
}

// ---------------------------------------------------------------------------
// k_wred_v1: grid 16 (one block per c). Phase 1: wsum_c[o*16+i] = sum over
// 1024 partial blocks (coalesced). Phase 2: v1[b,c,o] =
// squash_o((1/R) * wsum_c[o,:].x[b,c,:])  (R4-proven).
// ---------------------------------------------------------------------------
__global__ __launch_bounds__(256) void k_wred_v1(const float* __restrict__ part,
                                                 const float* __restrict__ x,
                                                 float* __restrict__ v1) {
    __shared__ float wsc[256];
    int c = blockIdx.x, t = threadIdx.x;
    float acc = 0.f;
    #pragma unroll 8
    for (int p = 0; p < 1024; ++p) acc += part[(size_t)p * 4096 + c * 256 + t];
    wsc[t] = acc;
    __syncthreads();
    int o = t & 15;
    #pragma unroll
    for (int bb = 0; bb < 2; ++bb) {
        int b = (t >> 4) + bb * 16;
        const float* xb = x + (b * 16 + c) * 16;
        float s = 0.f;
        #pragma unroll
        for (int i = 0; i < 16; ++i) s += wsc[o * 16 + i] * xb[i];
        s *= (1.0f / 16384.0f);
        float ns = s * s;
        #pragma unroll
        for (int d = 1; d < 16; d <<= 1) ns += __shfl_xor(ns, d);
        v1[b * 256 + c * 16 + o] = s * (sqrtf(ns) / (1.0f + ns));
    }
}

// k_vsum: v2 = squash(E/Z); vsum = v1 + v2
__global__ __launch_bounds__(256) void k_vsum(const float* __restrict__ E,
                                              const float* __restrict__ Z,
                                              const float* __restrict__ v1,
                                              float* __restrict__ vsum) {
    int t = blockIdx.x * 256 + threadIdx.x;
    float s = E[t] / Z[t >> 4];
    float ns = s * s;
    #pragma unroll
    for (int d = 1; d < 16; d <<= 1) ns += __shfl_xor(ns, d);
    vsum[t] = v1[t] + s * (sqrtf(ns) / (1.0f + ns));
}

// k_vout: final v = squash(E/Z) -> out
__global__ __launch_bounds__(256) void k_vout(const float* __restrict__ E,
                                              const float* __restrict__ Z,
                                              float* __restrict__ dst) {
    int t = blockIdx.x * 256 + threadIdx.x;
    float s = E[t] / Z[t >> 4];
    float ns = s * s;
    #pragma unroll
    for (int d = 1; d < 16; d <<= 1) ns += __shfl_xor(ns, d);
    dst[t] = s * (sqrtf(ns) / (1.0f + ns));
}

// ---------------------------------------------------------------------------
// k_route<REV>: one W16-streaming softmax pass (MODE-1 only now).
// Block 512 = 8 waves; grid (16 c, 64 bx). Wave wv owns pairs
// [bx*128 + wv*16, +16) = contiguous 16 KB; all 16 fragment loads issued up
// front. Per pair: one mfma_f32_32x32x16_f16; Lv per route-parity = 8 fma +
// shfl_xor(32); e = exp; accE/accZ. D-layout (HW-verified): lane->b=lane&31;
// reg j->row=(j&3)+8*(j>>2)+4*kh; row<16 even o=row, row>=16 odd o=row-16.
// Epilogue: 17 KB LDS tree + atomics. REV reverses the bx walk (L3 tail).
// ---------------------------------------------------------------------------
template <int REV>
__global__ __launch_bounds__(512, 2)
void k_route(const _Float16* __restrict__ W16,
             const float* __restrict__ x,
             const float* __restrict__ v,
             float* __restrict__ E,
             float* __restrict__ Z) {
    __shared__ float red[8 * 512 + 256];           // 17 KB epilogue scratch
    const int c = blockIdx.x;
    const int bxr = (int)blockIdx.y;
    const int bx = REV ? (63 - bxr) : bxr;
    const int tid = threadIdx.x;
    const int wv = tid >> 6;                       // [0,8)
    const int lane = tid & 63;
    const int b = lane & 31;                       // batch (N-col / D-col)
    const int kh = lane >> 5;                      // k-half

    half8_t Bh;
    {
        const float4* xb = (const float4*)(x + (b * 16 + c) * 16) + kh * 2;
        float4 x0 = xb[0], x1 = xb[1];
        float xv[8] = {x0.x, x0.y, x0.z, x0.w, x1.x, x1.y, x1.z, x1.w};
        #pragma unroll
        for (int j = 0; j < 8; ++j) Bh[j] = (_Float16)xv[j];
    }
    float vv[8];
    {
        const float4* vb = (const float4*)(v + (b * 16 + c) * 16);
        float4 v0 = vb[kh], v1 = vb[2 + kh];
        vv[0]=v0.x; vv[1]=v0.y; vv[2]=v0.z; vv[3]=v0.w;
        vv[4]=v1.x; vv[5]=v1.y; vv[6]=v1.z; vv[7]=v1.w;
    }

    const f32x16_t z16 = {0.f,0.f,0.f,0.f,0.f,0.f,0.f,0.f,
                          0.f,0.f,0.f,0.f,0.f,0.f,0.f,0.f};
    float accE[16];
    #pragma unroll
    for (int j = 0; j < 16; ++j) accE[j] = 0.f;
    float accZ0 = 0.f, accZ1 = 0.f;

    const uint4* base = (const uint4*)W16
        + ((size_t)(c * 8192 + bx * 128 + wv * 16)) * 64 + lane;

    uint4 f[16];
    #pragma unroll
    for (int p = 0; p < 16; ++p) f[p] = base[(size_t)p * 64];

    #pragma unroll
    for (int p = 0; p < 16; ++p) {
        half8_t Ah;
        *(uint4*)&Ah = f[p];
        f32x16_t t = __builtin_amdgcn_mfma_f32_32x32x16_f16(Ah, Bh, z16, 0, 0, 0);
        float pe = 0.f, po = 0.f;
        #pragma unroll
        for (int rb = 0; rb < 4; ++rb) {
            pe += t[rb] * vv[rb] + t[4 + rb] * vv[4 + rb];
            po += t[8 + rb] * vv[rb] + t[12 + rb] * vv[4 + rb];
        }
        pe += __shfl_xor(pe, 32);                  // join k-halves (o-halves)
        po += __shfl_xor(po, 32);
        float e0 = __expf(pe), e1 = __expf(po);
        accZ0 += e0;  accZ1 += e1;
        #pragma unroll
        for (int j = 0; j < 8; ++j)  accE[j] += e0 * t[j];
        #pragma unroll
        for (int j = 8; j < 16; ++j) accE[j] += e1 * t[j];
    }

    // ---- epilogue: LDS tree + atomics ----
    float4 e0 = make_float4(accE[0] + accE[8],  accE[1] + accE[9],
                            accE[2] + accE[10], accE[3] + accE[11]);
    float4 e1 = make_float4(accE[4] + accE[12], accE[5] + accE[13],
                            accE[6] + accE[14], accE[7] + accE[15]);
    *(float4*)&red[wv * 512 + b * 16 + 4 * kh]     = e0;
    *(float4*)&red[wv * 512 + b * 16 + 8 + 4 * kh] = e1;
    if (kh == 0) red[4096 + wv * 32 + b] = accZ0 + accZ1;
    __syncthreads();
    {
        float s = 0.f;
        #pragma unroll
        for (int w2 = 0; w2 < 8; ++w2) s += red[w2 * 512 + tid];
        atomicAdd(&E[(tid >> 4) * 256 + c * 16 + (tid & 15)], s);
    }
    if (tid < 32) {
        float sz = 0.f;
        #pragma unroll
        for (int w2 = 0; w2 < 8; ++w2) sz += red[4096 + w2 * 32 + tid];
        atomicAdd(&Z[tid * 16 + c], sz);
    }
}

// ---------------------------------------------------------------------------
// launch
// ---------------------------------------------------------------------------
extern "C" void kernel_launch(void* const* d_in, const int* in_sizes, int n_in,
                              void* d_out, int out_size, void* d_ws, size_t ws_size,
                              hipStream_t stream) {
    const float* x = (const float*)d_in[0];        // 8192 floats
    const float* W = (const float*)d_in[1];        // 67108864 floats (256 MB)
    float* out = (float*)d_out;                    // 8192 floats
    float* ws = (float*)d_ws;

    float* E2   = ws + 0;          // 8192
    float* Z2   = ws + 8192;       // 512
    float* E3   = ws + 8704;       // 8192
    float* Z3   = ws + 16896;      // 512   (zeroed region ends at 17408)
    float* v1   = ws + 17408;      // 8192
    float* vsum = ws + 25600;      // 8192
    float* part = ws + 65536;      // 4194304 floats (16 MB)
    _Float16* W16 = (_Float16*)(ws + 65536 + 4194304);   // 128 MB

    hipMemsetAsync(ws, 0, 17408 * sizeof(float), stream);

    // fused: fp32->fp16 fragment repack + r-sum partials (one W read)
    k_convsum<<<1024, 256, 0, stream>>>((const float4*)W, W16, part);
    k_wred_v1<<<16, 256, 0, stream>>>(part, x, v1);    // v1 = squash(wsum.x/R)

    // iter 2: logits = <u, v1>  (W16 pass, reverse: L3-warm from conv tail)
    k_route<1><<<dim3(16, 64), 512, 0, stream>>>(W16, x, v1, E2, Z2);
    k_vsum<<<32, 256, 0, stream>>>(E2, Z2, v1, vsum);  // vsum = v1 + squash(E2/Z2)

    // iter 3: logits = <u, v1+v2>  (W16 pass, forward)
    k_route<0><<<dim3(16, 64), 512, 0, stream>>>(W16, x, vsum, E3, Z3);
    k_vout<<<32, 256, 0, stream>>>(E3, Z3, out);
}